// Round 3
// baseline (108.367 us; speedup 1.0000x reference)
//
#include <hip/hip_runtime.h>
#include <hip/hip_bf16.h>
#include <math.h>

#define B 256
#define S 128
#define E 768
#define E4 192      // E/4 (float4 per row)
#define NA 30
#define NNEG 10

#define K2_KC 96    // k-chunk staged in LDS
#define K2_KR 192   // k-range per block (2 chunks), ksplit = 4

__device__ __forceinline__ float dot4(float4 a, float4 b) {
    return a.x * b.x + a.y * b.y + a.z * b.z + a.w * b.w;
}
__device__ __forceinline__ float wave_reduce_sum(float v) {
#pragma unroll
    for (int off = 32; off; off >>= 1) v += __shfl_down(v, off);
    return v;   // valid on lane 0
}
__device__ __forceinline__ float wave_reduce_max(float v) {
#pragma unroll
    for (int off = 32; off; off >>= 1) v = fmaxf(v, __shfl_down(v, off));
    return v;   // valid on lane 0
}

// ---------------- K1: q[b] = mean over s of x[b,s,:]  (+30 prep blocks) ----------------
__global__ __launch_bounds__(768) void mean_prep_kernel(const float* __restrict__ x,
                                                        const float* __restrict__ W_red,
                                                        const float* __restrict__ aspect_W,
                                                        float* __restrict__ q,
                                                        float* __restrict__ WredT,
                                                        float* __restrict__ invn) {
    int bid = blockIdx.x;
    int tid = threadIdx.x;
    __shared__ __align__(16) float4 part[4][E4];
    __shared__ float red[12];

    if (bid < B) {
        int b = bid;
        int c = tid % E4;     // float4 column
        int g = tid / E4;     // 0..3 (s-group)
        const float4* xb = (const float4*)(x + (size_t)b * S * E);
        float4 acc = make_float4(0.f, 0.f, 0.f, 0.f);
        for (int s = g * 32; s < g * 32 + 32; ++s) {
            float4 v = xb[(size_t)s * E4 + c];
            acc.x += v.x; acc.y += v.y; acc.z += v.z; acc.w += v.w;
        }
        part[g][c] = acc;
        __syncthreads();
        if (tid < E4) {
            float4 a0 = part[0][c], a1 = part[1][c], a2 = part[2][c], a3 = part[3][c];
            const float inv = 1.0f / (float)S;
            float4 r;
            r.x = (a0.x + a1.x + a2.x + a3.x) * inv;
            r.y = (a0.y + a1.y + a2.y + a3.y) * inv;
            r.z = (a0.z + a1.z + a2.z + a3.z) * inv;
            r.w = (a0.w + a1.w + a2.w + a3.w) * inv;
            ((float4*)q)[(size_t)b * E4 + c] = r;
        }
    } else {
        int a = bid - B;                       // 0..29
        // transpose one aspect's W_red column into a row
        WredT[(size_t)a * E + tid] = W_red[(size_t)tid * NA + a];
        // inverse norm of aspect row a
        int wave = tid >> 6, lane = tid & 63;
        float v = aspect_W[(size_t)a * E + tid];
        float ss = wave_reduce_sum(v * v);
        if (lane == 0) red[wave] = ss;
        __syncthreads();
        if (tid == 0) {
            float n = 0.f;
#pragma unroll
            for (int w = 0; w < 12; ++w) n += red[w];
            invn[a] = 1.0f / fmaxf(sqrtf(n), 1e-12f);
        }
    }
}

// ---------------- K2: qW partials (k-split GEMM 256x768x768) ----------------
// grid (4, 12, 4): b-tile 64, e-tile 64, k-range 192. Thread: 2 b-rows x 8 e-cols.
__global__ __launch_bounds__(256) void qw_partial_kernel(const float* __restrict__ q,
                                                         const float* __restrict__ W_att,
                                                         float* __restrict__ part) {
    int b0 = blockIdx.x * 64;
    int e0 = blockIdx.y * 64;
    int kz = blockIdx.z;
    int k0 = kz * K2_KR;
    int tid = threadIdx.x;

    __shared__ __align__(16) float qs[64][K2_KC + 4];   // stride 100: bank-safe
    __shared__ __align__(16) float ws[K2_KC][64];

    int r0 = (tid >> 3) * 2;        // 0,2,..,62
    int c0 = (tid & 7) * 8;         // 0,8,..,56

    float4 a00 = make_float4(0,0,0,0), a01 = make_float4(0,0,0,0);
    float4 a10 = make_float4(0,0,0,0), a11 = make_float4(0,0,0,0);

    for (int ch = 0; ch < 2; ++ch) {
        int kc0 = k0 + ch * K2_KC;
        {
            int row = tid >> 2, ks = (tid & 3) * 24;
            const float* src = q + (size_t)(b0 + row) * E + kc0 + ks;
#pragma unroll
            for (int j = 0; j < 6; ++j) {
                float4 v = *(const float4*)(src + 4 * j);
                *(float4*)&qs[row][ks + 4 * j] = v;
            }
        }
        for (int i = tid; i < K2_KC * 16; i += 256) {
            int row = i >> 4, e4 = (i & 15) * 4;
            *(float4*)&ws[row][e4] =
                *(const float4*)(W_att + (size_t)(kc0 + row) * E + e0 + e4);
        }
        __syncthreads();
#pragma unroll 4
        for (int k = 0; k < K2_KC; ++k) {
            float qa = qs[r0][k], qb = qs[r0 + 1][k];
            float4 w0 = *(const float4*)&ws[k][c0];
            float4 w1 = *(const float4*)&ws[k][c0 + 4];
            a00.x += qa * w0.x; a00.y += qa * w0.y; a00.z += qa * w0.z; a00.w += qa * w0.w;
            a01.x += qa * w1.x; a01.y += qa * w1.y; a01.z += qa * w1.z; a01.w += qa * w1.w;
            a10.x += qb * w0.x; a10.y += qb * w0.y; a10.z += qb * w0.z; a10.w += qb * w0.w;
            a11.x += qb * w1.x; a11.y += qb * w1.y; a11.z += qb * w1.z; a11.w += qb * w1.w;
        }
        __syncthreads();
    }
    float* dst = part + ((size_t)kz * B + b0 + r0) * E + e0 + c0;
    *(float4*)dst = a00; *(float4*)(dst + 4) = a01;
    *(float4*)(dst + E) = a10; *(float4*)(dst + E + 4) = a11;
}

// ---------------- K3: scores[b,s] = x[b,s,:] . qW[b] (sums partials in-stage) ----------------
// grid 2048: (b, 16-row chunk). 4 waves x 4 rows each.
__global__ __launch_bounds__(256) void score_kernel(const float* __restrict__ x,
                                                    const float* __restrict__ part,
                                                    const float* __restrict__ b_att,
                                                    float* __restrict__ sc) {
    int b  = blockIdx.x >> 3;
    int sb = (blockIdx.x & 7) * 16;
    int tid = threadIdx.x, wave = tid >> 6, lane = tid & 63;
    const int N4 = B * E / 4;
    __shared__ __align__(16) float4 qw4[E4];
    if (tid < E4) {
        const float4* p = (const float4*)part;
        size_t base = (size_t)b * E4 + tid;
        float4 s0 = p[base], s1 = p[base + N4], s2 = p[base + 2 * N4], s3 = p[base + 3 * N4];
        float4 bb = ((const float4*)b_att)[tid];
        float4 r;
        r.x = s0.x + s1.x + s2.x + s3.x + bb.x;
        r.y = s0.y + s1.y + s2.y + s3.y + bb.y;
        r.z = s0.z + s1.z + s2.z + s3.z + bb.z;
        r.w = s0.w + s1.w + s2.w + s3.w + bb.w;
        qw4[tid] = r;
    }
    __syncthreads();
    const float4* xb = (const float4*)(x + (size_t)b * S * E);
#pragma unroll
    for (int i = 0; i < 4; ++i) {
        int s = sb + wave * 4 + i;
        const float4* row = xb + (size_t)s * E4;
        float d = 0.f;
#pragma unroll
        for (int j = 0; j < 3; ++j)
            d += dot4(row[lane + 64 * j], qw4[lane + 64 * j]);
        d = wave_reduce_sum(d);
        if (lane == 0) sc[b * S + s] = d;
    }
}

// ---------------- K4: softmax(scores) then z[b] = attn . x[b]  (e-split x2) ----------------
__global__ __launch_bounds__(768) void zvec_kernel(const float* __restrict__ x,
                                                   const float* __restrict__ sc,
                                                   float* __restrict__ z_s) {
    int b = blockIdx.x;
    int half = blockIdx.y;              // 0/1: which 96 float4 columns
    int tid = threadIdx.x, wave = tid >> 6, lane = tid & 63;
    __shared__ float att[S];
    __shared__ float red[4];
    float v = 0.f;
    if (tid < S) {
        v = sc[b * S + tid];
        float m = wave_reduce_max(v);
        if (lane == 0) red[wave] = m;   // waves 0,1
    }
    __syncthreads();
    float gm = fmaxf(red[0], red[1]);
    if (tid < S) {
        float ex = expf(v - gm);
        att[tid] = ex;
        float ssum = wave_reduce_sum(ex);
        if (lane == 0) red[2 + wave] = ssum;
    }
    __syncthreads();
    float tot = red[2] + red[3];
    if (tid < S) att[tid] = att[tid] / tot;
    __syncthreads();

    int c = tid % 96;                   // local float4 column
    int g = tid / 96;                   // 0..7 (s-group of 16)
    const float4* xb = (const float4*)(x + (size_t)b * S * E) + half * 96;
    float4 acc = make_float4(0.f, 0.f, 0.f, 0.f);
    for (int s = g * 16; s < g * 16 + 16; ++s) {
        float w = att[s];
        float4 xv = xb[(size_t)s * E4 + c];
        acc.x += w * xv.x; acc.y += w * xv.y; acc.z += w * xv.z; acc.w += w * xv.w;
    }
    __shared__ __align__(16) float4 part[8][96];
    part[g][c] = acc;
    __syncthreads();
    if (tid < 96) {
        float4 r = make_float4(0.f, 0.f, 0.f, 0.f);
#pragma unroll
        for (int gg = 0; gg < 8; ++gg) {
            float4 a = part[gg][tid];
            r.x += a.x; r.y += a.y; r.z += a.z; r.w += a.w;
        }
        ((float4*)z_s)[(size_t)b * E4 + half * 96 + tid] = r;
    }
}

// ---------------- K5: composition softmax + reconstruction + margin partials ----------------
__global__ __launch_bounds__(256) void recon_margin_kernel(const float* __restrict__ z_s,
                                                           const float* __restrict__ WredT,
                                                           const float* __restrict__ b_red,
                                                           const float* __restrict__ aspect_W,
                                                           const int* __restrict__ neg_idx,
                                                           float* __restrict__ recon,
                                                           float* __restrict__ mpart) {
    int b = blockIdx.x;
    int tid = threadIdx.x, wave = tid >> 6, lane = tid & 63;
    __shared__ __align__(16) float4 z4[E4];
    __shared__ float comp[NA];
    __shared__ __align__(16) float r_sh[E];
    __shared__ float red[4];
    __shared__ float dots[12];

    if (tid < E4) z4[tid] = ((const float4*)(z_s + (size_t)b * E))[tid];
    __syncthreads();

    for (int a = wave; a < NA; a += 4) {
        const float4* wr = (const float4*)(WredT + (size_t)a * E);
        float d = 0.f;
#pragma unroll
        for (int j = 0; j < 3; ++j)
            d += dot4(wr[lane + 64 * j], z4[lane + 64 * j]);
        d = wave_reduce_sum(d);
        if (lane == 0) comp[a] = d + b_red[a];
    }
    __syncthreads();

    if (wave == 0) {
        float v = (lane < NA) ? comp[lane] : -3.4e38f;
        float m = wave_reduce_max(v);
        m = __shfl(m, 0);
        float e = (lane < NA) ? expf(v - m) : 0.f;
        float ssum = wave_reduce_sum(e);
        ssum = __shfl(ssum, 0);
        if (lane < NA) comp[lane] = e / ssum;
    }
    __syncthreads();

    float r0 = 0.f, r1 = 0.f, r2 = 0.f;
    for (int a = 0; a < NA; ++a) {
        float cm = comp[a];
        const float* ar = aspect_W + (size_t)a * E;
        r0 += cm * ar[tid];
        r1 += cm * ar[tid + 256];
        r2 += cm * ar[tid + 512];
    }
    float* rb = recon + (size_t)b * E;
    rb[tid] = r0; rb[tid + 256] = r1; rb[tid + 512] = r2;
    r_sh[tid] = r0; r_sh[tid + 256] = r1; r_sh[tid + 512] = r2;
    float sq = r0 * r0 + r1 * r1 + r2 * r2;
    sq = wave_reduce_sum(sq);
    if (lane == 0) red[wave] = sq;
    __syncthreads();
    float inv = 1.0f / fmaxf(sqrtf(red[0] + red[1] + red[2] + red[3]), 1e-12f);

    for (int d = wave; d < NNEG + 1; d += 4) {
        int row = (d == 0) ? b : neg_idx[b * NNEG + (d - 1)];
        const float4* zr = (const float4*)(z_s + (size_t)row * E);
        const float4* rr = (const float4*)r_sh;
        float acc = 0.f;
#pragma unroll
        for (int j = 0; j < 3; ++j)
            acc += dot4(zr[lane + 64 * j], rr[lane + 64 * j]);
        acc = wave_reduce_sum(acc);
        if (lane == 0) dots[d] = acc;
    }
    __syncthreads();
    if (tid == 0) {
        float pos = dots[0] * inv;
        float ssum = 0.f;
        for (int n = 1; n <= NNEG; ++n)
            ssum += fmaxf(1.f - pos + dots[n] * inv, 0.f);
        mpart[b] = ssum;
    }
}

// ---------------- K6: orthogonality reg + final loss (single block, LDS-staged) ----------------
__global__ __launch_bounds__(1024) void ortho_loss_kernel(const float* __restrict__ aspect_W,
                                                          const float* __restrict__ invn,
                                                          const float* __restrict__ mpart,
                                                          float* __restrict__ loss_out) {
    int tid = threadIdx.x, wave = tid >> 6, lane = tid & 63;
    __shared__ __align__(16) float4 tn[NA * E4];   // 92160 B: normalized aspect rows
    __shared__ float red[16], red2[16];

    for (int i = tid; i < NA * E4; i += 1024) {
        int a = i / E4;
        float s = invn[a];
        float4 v = ((const float4*)aspect_W)[i];
        v.x *= s; v.y *= s; v.z *= s; v.w *= s;
        tn[i] = v;
    }
    __syncthreads();

    // 900 pairwise dots, one per wave-round
    float acc = 0.f;
    for (int p = wave; p < NA * NA; p += 16) {
        int i = p / NA, j = p % NA;
        float d = 0.f;
#pragma unroll
        for (int jj = 0; jj < 3; ++jj)
            d += dot4(tn[i * E4 + lane + 64 * jj], tn[j * E4 + lane + 64 * jj]);
        d = wave_reduce_sum(d);
        if (lane == 0) {
            float g = d - ((i == j) ? 1.f : 0.f);
            acc += g * g;
        }
    }
    if (lane == 0) red[wave] = acc;

    // margin partial sum (256 entries, waves 0..3)
    float m = (tid < B) ? mpart[tid] : 0.f;
    m = wave_reduce_sum(m);
    if (lane == 0) red2[wave] = m;
    __syncthreads();

    if (tid == 0) {
        float fr = 0.f, ms = 0.f;
#pragma unroll
        for (int w = 0; w < 16; ++w) { fr += red[w]; ms += red2[w]; }
        loss_out[0] = sqrtf(fr) + ms * (1.0f / (float)(B * NNEG));
    }
}

extern "C" void kernel_launch(void* const* d_in, const int* in_sizes, int n_in,
                              void* d_out, int out_size, void* d_ws, size_t ws_size,
                              hipStream_t stream) {
    const float* x        = (const float*)d_in[0];
    const float* W_att    = (const float*)d_in[1];
    const float* b_att    = (const float*)d_in[2];
    const float* W_red    = (const float*)d_in[3];
    const float* b_red    = (const float*)d_in[4];
    const float* aspect_W = (const float*)d_in[5];
    const int*   neg_idx  = (const int*)d_in[6];

    float* out   = (float*)d_out;
    float* z_s   = out;                       // [B,E]
    float* recon = out + (size_t)B * E;       // [B,E]
    float* loss  = out + (size_t)2 * B * E;   // [1]

    float* ws    = (float*)d_ws;
    float* q     = ws;                        // B*E
    float* part2 = q + (size_t)B * E;         // 4*B*E
    float* sc    = part2 + (size_t)4 * B * E; // B*S
    float* WredT = sc + (size_t)B * S;        // NA*E
    float* invn  = WredT + (size_t)NA * E;    // 32
    float* mpart = invn + 32;                 // B

    mean_prep_kernel<<<B + NA, 768, 0, stream>>>(x, W_red, aspect_W, q, WredT, invn);
    qw_partial_kernel<<<dim3(4, 12, 4), 256, 0, stream>>>(q, W_att, part2);
    score_kernel<<<2048, 256, 0, stream>>>(x, part2, b_att, sc);
    zvec_kernel<<<dim3(B, 2), 768, 0, stream>>>(x, sc, z_s);
    recon_margin_kernel<<<B, 256, 0, stream>>>(z_s, WredT, b_red, aspect_W, neg_idx, recon, mpart);
    ortho_loss_kernel<<<1, 1024, 0, stream>>>(aspect_W, invn, mpart, loss);
}

// Round 4
// 82.561 us; speedup vs baseline: 1.3126x; 1.3126x over previous
//
#include <hip/hip_runtime.h>
#include <hip/hip_bf16.h>
#include <math.h>

#define B 256
#define S 128
#define E 768
#define E4 192      // E/4 (float4 per row)
#define NA 30
#define NNEG 10

#define K2_KC 96    // k-chunk staged in LDS
#define K2_KR 192   // k-range per block (2 chunks), ksplit = 4

__device__ __forceinline__ float dot4(float4 a, float4 b) {
    return a.x * b.x + a.y * b.y + a.z * b.z + a.w * b.w;
}
__device__ __forceinline__ float wave_reduce_sum(float v) {
#pragma unroll
    for (int off = 32; off; off >>= 1) v += __shfl_down(v, off);
    return v;   // valid on lane 0
}
__device__ __forceinline__ float wave_reduce_max(float v) {
#pragma unroll
    for (int off = 32; off; off >>= 1) v = fmaxf(v, __shfl_down(v, off));
    return v;   // valid on lane 0
}

// ---------------- K1: q[b] = mean over s of x[b,s,:]  (+30 prep blocks) ----------------
__global__ __launch_bounds__(768) void mean_prep_kernel(const float* __restrict__ x,
                                                        const float* __restrict__ W_red,
                                                        const float* __restrict__ aspect_W,
                                                        float* __restrict__ q,
                                                        float* __restrict__ WredT,
                                                        float* __restrict__ invn) {
    int bid = blockIdx.x;
    int tid = threadIdx.x;
    __shared__ __align__(16) float4 part[4][E4];
    __shared__ float red[12];

    if (bid < B) {
        int b = bid;
        int c = tid % E4;     // float4 column
        int g = tid / E4;     // 0..3 (s-group)
        const float4* xb = (const float4*)(x + (size_t)b * S * E);
        float4 acc = make_float4(0.f, 0.f, 0.f, 0.f);
        for (int s = g * 32; s < g * 32 + 32; ++s) {
            float4 v = xb[(size_t)s * E4 + c];
            acc.x += v.x; acc.y += v.y; acc.z += v.z; acc.w += v.w;
        }
        part[g][c] = acc;
        __syncthreads();
        if (tid < E4) {
            float4 a0 = part[0][c], a1 = part[1][c], a2 = part[2][c], a3 = part[3][c];
            const float inv = 1.0f / (float)S;
            float4 r;
            r.x = (a0.x + a1.x + a2.x + a3.x) * inv;
            r.y = (a0.y + a1.y + a2.y + a3.y) * inv;
            r.z = (a0.z + a1.z + a2.z + a3.z) * inv;
            r.w = (a0.w + a1.w + a2.w + a3.w) * inv;
            ((float4*)q)[(size_t)b * E4 + c] = r;
        }
    } else {
        int a = bid - B;                       // 0..29
        WredT[(size_t)a * E + tid] = W_red[(size_t)tid * NA + a];
        int wave = tid >> 6, lane = tid & 63;
        float v = aspect_W[(size_t)a * E + tid];
        float ss = wave_reduce_sum(v * v);
        if (lane == 0) red[wave] = ss;
        __syncthreads();
        if (tid == 0) {
            float n = 0.f;
#pragma unroll
            for (int w = 0; w < 12; ++w) n += red[w];
            invn[a] = 1.0f / fmaxf(sqrtf(n), 1e-12f);
        }
    }
}

// ---------------- K2: qW partials (k-split GEMM 256x768x768) ----------------
__global__ __launch_bounds__(256) void qw_partial_kernel(const float* __restrict__ q,
                                                         const float* __restrict__ W_att,
                                                         float* __restrict__ part) {
    int b0 = blockIdx.x * 64;
    int e0 = blockIdx.y * 64;
    int kz = blockIdx.z;
    int k0 = kz * K2_KR;
    int tid = threadIdx.x;

    __shared__ __align__(16) float qs[64][K2_KC + 4];
    __shared__ __align__(16) float ws[K2_KC][64];

    int r0 = (tid >> 3) * 2;
    int c0 = (tid & 7) * 8;

    float4 a00 = make_float4(0,0,0,0), a01 = make_float4(0,0,0,0);
    float4 a10 = make_float4(0,0,0,0), a11 = make_float4(0,0,0,0);

    for (int ch = 0; ch < 2; ++ch) {
        int kc0 = k0 + ch * K2_KC;
        {
            int row = tid >> 2, ks = (tid & 3) * 24;
            const float* src = q + (size_t)(b0 + row) * E + kc0 + ks;
#pragma unroll
            for (int j = 0; j < 6; ++j) {
                float4 v = *(const float4*)(src + 4 * j);
                *(float4*)&qs[row][ks + 4 * j] = v;
            }
        }
        for (int i = tid; i < K2_KC * 16; i += 256) {
            int row = i >> 4, e4 = (i & 15) * 4;
            *(float4*)&ws[row][e4] =
                *(const float4*)(W_att + (size_t)(kc0 + row) * E + e0 + e4);
        }
        __syncthreads();
#pragma unroll 4
        for (int k = 0; k < K2_KC; ++k) {
            float qa = qs[r0][k], qb = qs[r0 + 1][k];
            float4 w0 = *(const float4*)&ws[k][c0];
            float4 w1 = *(const float4*)&ws[k][c0 + 4];
            a00.x += qa * w0.x; a00.y += qa * w0.y; a00.z += qa * w0.z; a00.w += qa * w0.w;
            a01.x += qa * w1.x; a01.y += qa * w1.y; a01.z += qa * w1.z; a01.w += qa * w1.w;
            a10.x += qb * w0.x; a10.y += qb * w0.y; a10.z += qb * w0.z; a10.w += qb * w0.w;
            a11.x += qb * w1.x; a11.y += qb * w1.y; a11.z += qb * w1.z; a11.w += qb * w1.w;
        }
        __syncthreads();
    }
    float* dst = part + ((size_t)kz * B + b0 + r0) * E + e0 + c0;
    *(float4*)dst = a00; *(float4*)(dst + 4) = a01;
    *(float4*)(dst + E) = a10; *(float4*)(dst + E + 4) = a11;
}

// ---------------- K3: fused scores + softmax + z  (block per b) ----------------
// Sweep 1: scores[s] = x[b,s,:].qW[b] (12 waves, L3-resident x).
// Softmax in LDS. Sweep 2: z = att . x[b] (L2-hit, block-local reuse).
__global__ __launch_bounds__(768) void attn_fused_kernel(const float* __restrict__ x,
                                                         const float* __restrict__ part,
                                                         const float* __restrict__ b_att,
                                                         float* __restrict__ z_s) {
    int b = blockIdx.x;
    int tid = threadIdx.x, wave = tid >> 6, lane = tid & 63;
    const int N4 = B * E / 4;
    __shared__ __align__(16) float4 qw4[E4];
    __shared__ float att[S];
    __shared__ float red[8];
    __shared__ __align__(16) float4 zpart[4][E4];

    // stage qW[b] = sum of 4 k-partials + b_att
    if (tid < E4) {
        const float4* p = (const float4*)part;
        size_t base = (size_t)b * E4 + tid;
        float4 s0 = p[base], s1 = p[base + N4], s2 = p[base + 2 * N4], s3 = p[base + 3 * N4];
        float4 bb = ((const float4*)b_att)[tid];
        float4 r;
        r.x = s0.x + s1.x + s2.x + s3.x + bb.x;
        r.y = s0.y + s1.y + s2.y + s3.y + bb.y;
        r.z = s0.z + s1.z + s2.z + s3.z + bb.z;
        r.w = s0.w + s1.w + s2.w + s3.w + bb.w;
        qw4[tid] = r;
    }
    __syncthreads();

    const float4* xb = (const float4*)(x + (size_t)b * S * E);

    // sweep 1: scores
    for (int s = wave; s < S; s += 12) {
        const float4* row = xb + (size_t)s * E4;
        float d = 0.f;
#pragma unroll
        for (int j = 0; j < 3; ++j)
            d += dot4(row[lane + 64 * j], qw4[lane + 64 * j]);
        d = wave_reduce_sum(d);
        if (lane == 0) att[s] = d;
    }
    __syncthreads();

    // softmax over 128 (waves 0,1)
    float v = (tid < S) ? att[tid] : -3.4e38f;
    if (tid < S) {
        float m = wave_reduce_max(v);
        if (lane == 0) red[wave] = m;
    }
    __syncthreads();
    float gm = fmaxf(red[0], red[1]);
    float ex = 0.f;
    if (tid < S) {
        ex = expf(v - gm);
        float ss = wave_reduce_sum(ex);
        if (lane == 0) red[4 + wave] = ss;
    }
    __syncthreads();
    float tot = red[4] + red[5];
    if (tid < S) att[tid] = ex / tot;
    __syncthreads();

    // sweep 2: z[b] = att . x[b]
    int c = tid % E4, g = tid / E4;
    float4 acc = make_float4(0.f, 0.f, 0.f, 0.f);
    for (int s = g * 32; s < g * 32 + 32; ++s) {
        float w = att[s];
        float4 xv = xb[(size_t)s * E4 + c];
        acc.x += w * xv.x; acc.y += w * xv.y; acc.z += w * xv.z; acc.w += w * xv.w;
    }
    zpart[g][c] = acc;
    __syncthreads();
    if (tid < E4) {
        float4 a0 = zpart[0][c], a1 = zpart[1][c], a2 = zpart[2][c], a3 = zpart[3][c];
        float4 r;
        r.x = a0.x + a1.x + a2.x + a3.x;
        r.y = a0.y + a1.y + a2.y + a3.y;
        r.z = a0.z + a1.z + a2.z + a3.z;
        r.w = a0.w + a1.w + a2.w + a3.w;
        ((float4*)z_s)[(size_t)b * E4 + c] = r;
    }
}

// ---------------- K4: composition softmax + reconstruction + margin partials ----------------
__global__ __launch_bounds__(256) void recon_margin_kernel(const float* __restrict__ z_s,
                                                           const float* __restrict__ WredT,
                                                           const float* __restrict__ b_red,
                                                           const float* __restrict__ aspect_W,
                                                           const int* __restrict__ neg_idx,
                                                           float* __restrict__ recon,
                                                           float* __restrict__ mpart) {
    int b = blockIdx.x;
    int tid = threadIdx.x, wave = tid >> 6, lane = tid & 63;
    __shared__ __align__(16) float4 z4[E4];
    __shared__ float comp[NA];
    __shared__ __align__(16) float r_sh[E];
    __shared__ float red[4];
    __shared__ float dots[12];

    if (tid < E4) z4[tid] = ((const float4*)(z_s + (size_t)b * E))[tid];
    __syncthreads();

    for (int a = wave; a < NA; a += 4) {
        const float4* wr = (const float4*)(WredT + (size_t)a * E);
        float d = 0.f;
#pragma unroll
        for (int j = 0; j < 3; ++j)
            d += dot4(wr[lane + 64 * j], z4[lane + 64 * j]);
        d = wave_reduce_sum(d);
        if (lane == 0) comp[a] = d + b_red[a];
    }
    __syncthreads();

    if (wave == 0) {
        float v = (lane < NA) ? comp[lane] : -3.4e38f;
        float m = wave_reduce_max(v);
        m = __shfl(m, 0);
        float e = (lane < NA) ? expf(v - m) : 0.f;
        float ssum = wave_reduce_sum(e);
        ssum = __shfl(ssum, 0);
        if (lane < NA) comp[lane] = e / ssum;
    }
    __syncthreads();

    float r0 = 0.f, r1 = 0.f, r2 = 0.f;
    for (int a = 0; a < NA; ++a) {
        float cm = comp[a];
        const float* ar = aspect_W + (size_t)a * E;
        r0 += cm * ar[tid];
        r1 += cm * ar[tid + 256];
        r2 += cm * ar[tid + 512];
    }
    float* rb = recon + (size_t)b * E;
    rb[tid] = r0; rb[tid + 256] = r1; rb[tid + 512] = r2;
    r_sh[tid] = r0; r_sh[tid + 256] = r1; r_sh[tid + 512] = r2;
    float sq = r0 * r0 + r1 * r1 + r2 * r2;
    sq = wave_reduce_sum(sq);
    if (lane == 0) red[wave] = sq;
    __syncthreads();
    float inv = 1.0f / fmaxf(sqrtf(red[0] + red[1] + red[2] + red[3]), 1e-12f);

    for (int d = wave; d < NNEG + 1; d += 4) {
        int row = (d == 0) ? b : neg_idx[b * NNEG + (d - 1)];
        const float4* zr = (const float4*)(z_s + (size_t)row * E);
        const float4* rr = (const float4*)r_sh;
        float acc = 0.f;
#pragma unroll
        for (int j = 0; j < 3; ++j)
            acc += dot4(zr[lane + 64 * j], rr[lane + 64 * j]);
        acc = wave_reduce_sum(acc);
        if (lane == 0) dots[d] = acc;
    }
    __syncthreads();
    if (tid == 0) {
        float pos = dots[0] * inv;
        float ssum = 0.f;
        for (int n = 1; n <= NNEG; ++n)
            ssum += fmaxf(1.f - pos + dots[n] * inv, 0.f);
        mpart[b] = ssum;
    }
}

// ---------------- K5: per-row orthogonality partial (30 blocks) ----------------
__global__ __launch_bounds__(256) void ortho_kernel(const float* __restrict__ aspect_W,
                                                    const float* __restrict__ invn,
                                                    float* __restrict__ Gpart) {
    int i = blockIdx.x;
    int tid = threadIdx.x, wave = tid >> 6, lane = tid & 63;
    __shared__ __align__(16) float4 ti[E4];
    __shared__ float red2[4];
    float inv_i = invn[i];
    if (tid < E4) {
        float4 v = ((const float4*)aspect_W)[(size_t)i * E4 + tid];
        v.x *= inv_i; v.y *= inv_i; v.z *= inv_i; v.w *= inv_i;
        ti[tid] = v;
    }
    __syncthreads();
    float acc = 0.f;
    for (int j = wave; j < NA; j += 4) {
        const float4* aj = (const float4*)(aspect_W + (size_t)j * E);
        float d = 0.f;
#pragma unroll
        for (int jj = 0; jj < 3; ++jj)
            d += dot4(aj[lane + 64 * jj], ti[lane + 64 * jj]);
        d = wave_reduce_sum(d);
        if (lane == 0) {
            float g = d * invn[j] - ((i == j) ? 1.f : 0.f);
            acc += g * g;
        }
    }
    if (lane == 0) red2[wave] = acc;
    __syncthreads();
    if (tid == 0) Gpart[i] = red2[0] + red2[1] + red2[2] + red2[3];
}

// ---------------- K6: final scalar loss ----------------
__global__ __launch_bounds__(256) void loss_kernel(const float* __restrict__ Gpart,
                                                   const float* __restrict__ mpart,
                                                   float* __restrict__ loss_out) {
    int tid = threadIdx.x, wave = tid >> 6, lane = tid & 63;
    __shared__ float ra[4], rb[4];
    float fr = (tid < NA) ? Gpart[tid] : 0.f;
    fr = wave_reduce_sum(fr);
    if (lane == 0) ra[wave] = fr;
    float mp = mpart[tid];
    mp = wave_reduce_sum(mp);
    if (lane == 0) rb[wave] = mp;
    __syncthreads();
    if (tid == 0) {
        float frob = sqrtf(ra[0] + ra[1] + ra[2] + ra[3]);
        float msum = rb[0] + rb[1] + rb[2] + rb[3];
        loss_out[0] = frob + msum * (1.0f / (float)(B * NNEG));
    }
}

extern "C" void kernel_launch(void* const* d_in, const int* in_sizes, int n_in,
                              void* d_out, int out_size, void* d_ws, size_t ws_size,
                              hipStream_t stream) {
    const float* x        = (const float*)d_in[0];
    const float* W_att    = (const float*)d_in[1];
    const float* b_att    = (const float*)d_in[2];
    const float* W_red    = (const float*)d_in[3];
    const float* b_red    = (const float*)d_in[4];
    const float* aspect_W = (const float*)d_in[5];
    const int*   neg_idx  = (const int*)d_in[6];

    float* out   = (float*)d_out;
    float* z_s   = out;                       // [B,E]
    float* recon = out + (size_t)B * E;       // [B,E]
    float* loss  = out + (size_t)2 * B * E;   // [1]

    float* ws    = (float*)d_ws;
    float* q     = ws;                        // B*E
    float* part2 = q + (size_t)B * E;         // 4*B*E
    float* WredT = part2 + (size_t)4 * B * E; // NA*E
    float* invn  = WredT + (size_t)NA * E;    // 32
    float* Gpart = invn + 32;                 // 32
    float* mpart = Gpart + 32;                // B

    mean_prep_kernel<<<B + NA, 768, 0, stream>>>(x, W_red, aspect_W, q, WredT, invn);
    qw_partial_kernel<<<dim3(4, 12, 4), 256, 0, stream>>>(q, W_att, part2);
    attn_fused_kernel<<<B, 768, 0, stream>>>(x, part2, b_att, z_s);
    recon_margin_kernel<<<B, 256, 0, stream>>>(z_s, WredT, b_red, aspect_W, neg_idx, recon, mpart);
    ortho_kernel<<<NA, 256, 0, stream>>>(aspect_W, invn, Gpart);
    loss_kernel<<<1, 256, 0, stream>>>(Gpart, mpart, loss);
}